// Round 1
// 536.795 us; speedup vs baseline: 1.0123x; 1.0123x over previous
//
#include <hip/hip_runtime.h>
#include <hip/hip_bf16.h>
#include <math.h>

#define BATCH 4096
#define HID 256
#define OUT_W 15

typedef unsigned short ushort_t;
typedef unsigned int uint_t;

using bf16x8 = __attribute__((ext_vector_type(8))) short;
using f32x4v = __attribute__((ext_vector_type(4))) float;

__device__ __forceinline__ float sigf(float x) { return 1.0f / (1.0f + __expf(-x)); }
__device__ __forceinline__ float tanh_fast(float x) { return 1.0f - 2.0f / (__expf(2.0f * x) + 1.0f); }
__device__ __forceinline__ float bf2f(ushort_t u) { return __uint_as_float(((uint_t)u) << 16); }
__device__ __forceinline__ ushort_t f2bf(float x) {
    uint_t b = __float_as_uint(x);
    return (ushort_t)((b + 0x7fffu + ((b >> 16) & 1u)) >> 16);
}

// ---------------------------------------------------------------------------
// Prep: W_ih transpose, per-step biases, samp tables, mlp transposes,
// packed conv1 weights w1p[ic][12], conv2 B-fragments Btg[tap][oc][ic] bf16,
// W_hh -> bf16 [n][k].
// ---------------------------------------------------------------------------
__global__ __launch_bounds__(256) void prep_kernel(
    const float* __restrict__ W_ih, const float* __restrict__ W_hh,
    const float* __restrict__ b_ih, const float* __restrict__ b_hh,
    const float* __restrict__ addr_emb, const float* __restrict__ pid_emb,
    const float* __restrict__ sid_emb,
    const float* __restrict__ mlp_w2, const float* __restrict__ mlp_w3,
    const float* __restrict__ conv1_w, const float* __restrict__ conv1_b,
    const float* __restrict__ conv2_w,
    float* __restrict__ W_ih_T, ushort_t* __restrict__ Wb,
    float* __restrict__ bias_all, float* __restrict__ pid_rows,
    float* __restrict__ sid_rows, float* __restrict__ w2t, float* __restrict__ w3t,
    float* __restrict__ w1p, ushort_t* __restrict__ Btg)
{
    int blk = blockIdx.x, t = threadIdx.x;
    if (blk < 112) {
        // W_ih (1024x432) -> W_ih_T (432x1024)
        __shared__ float tile[64][65];
        int j0 = (blk & 15) * 64;
        int k0 = (blk >> 4) * 64;
        for (int i = t; i < 4096; i += 256) {
            int r = i >> 6, c = i & 63;
            int k = k0 + c;
            tile[r][c] = (k < 432) ? W_ih[(size_t)(j0 + r) * 432 + k] : 0.f;
        }
        __syncthreads();
        for (int i = t; i < 4096; i += 256) {
            int r = i >> 6, c = i & 63;
            int k = k0 + r;
            if (k < 432) W_ih_T[(size_t)k * 1024 + j0 + c] = tile[c][r];
        }
    } else if (blk == 112) {
        const int aids[7] = {0, 1, 4, 2, 3, 5, 6};
        for (int s = 0; s < 7; s++) {
            int aid = aids[s];
            for (int j = t; j < 1024; j += 256) {
                float v = b_ih[j] + b_hh[j];
                #pragma unroll
                for (int k = 0; k < 16; k++)
                    v += addr_emb[aid * 16 + k] * W_ih[(size_t)j * 432 + 416 + k];
                bias_all[s * 1024 + j] = v;
            }
        }
    } else if (blk == 113) {
        for (int p = 0; p < 3; p++)
            for (int j = t; j < 1024; j += 256) {
                float v = 0.f;
                #pragma unroll
                for (int k = 0; k < 16; k++)
                    v += pid_emb[p * 16 + k] * W_ih[(size_t)j * 432 + 400 + k];
                pid_rows[p * 1024 + j] = v;
            }
        for (int p = 0; p < 2; p++)
            for (int j = t; j < 1024; j += 256) {
                float v = 0.f;
                #pragma unroll
                for (int k = 0; k < 16; k++)
                    v += sid_emb[p * 16 + k] * W_ih[(size_t)j * 432 + 400 + k];
                sid_rows[p * 1024 + j] = v;
            }
    } else if (blk == 114) {
        for (int i = t; i < 10000; i += 256) {
            int o = i / 100, k = i % 100;
            w2t[k * 100 + o] = mlp_w2[i];
        }
        for (int i = t; i < 1600; i += 256) {
            int o = i / 100, k = i % 100;
            w3t[k * 16 + o] = mlp_w3[i];
        }
    } else if (blk == 115) {
        for (int i = t; i < 384; i += 256) {
            int ic = i / 12, k = i % 12;
            float v = 0.f;
            if (k < 9) v = conv1_w[ic * 9 + k];
            else if (k == 9) v = conv1_b[ic];
            w1p[i] = v;
        }
        // Btg[(tap*16 + oc)*32 + ic] = conv2_w[(oc*32+ic)*9 + tap]
        for (int i = t; i < 4608; i += 256) {
            int tap = i >> 9;
            int rem = i & 511;
            int oc = rem >> 5, ic = rem & 31;
            Btg[i] = f2bf(conv2_w[(size_t)(oc * 32 + ic) * 9 + tap]);
        }
    } else {
        // W_hh (1024x256) fp32 -> bf16, same [n][k] layout
        int seg = blk - 116;  // 0..7
        for (int i = seg * 32768 + t; i < (seg + 1) * 32768; i += 256)
            Wb[i] = f2bf(W_hh[i]);
    }
}

// ---------------------------------------------------------------------------
// Conv encoder v3: two half-image phases over a 17-row ring buffer.
//   512 threads, LDS ~70 KB -> 2 blocks/CU (16 waves/CU vs 4 before).
//   Phase ph (0,1): conv1 computes c1 rows 16ph..16ph+15 (1 col x 32 ic per
//   thread); conv2 computes output rows 8ph..8ph+7 (1 row per wave, 9 MFMAs).
//   Ring: buffer row = (c1row+1) mod 17 -> the shared halo row (c1 row 15)
//   survives phase 0 with no copy.  Obs staged per phase (33x68 f32); the
//   phase-1 stage is issued alongside phase-0 MFMAs to hide global latency.
//   cE: even cols 0..30 (16 pos), cO: odd cols -1..31 (17 pos), pos stride
//   40 ushorts (80 B) -> conflict-free A-frag ds_read_b128 (as before).
// ---------------------------------------------------------------------------
#define CE_RS 640   // cE row stride in ushorts (16 pos * 40)
#define CO_RS 680   // cO row stride in ushorts (17 pos * 40)
__global__ __launch_bounds__(512, 4) void conv_kernel(
    const float* __restrict__ obs, const float* __restrict__ w1p,
    const ushort_t* __restrict__ Btg, const float* __restrict__ b2,
    float* __restrict__ obs_emb)
{
    __shared__ __align__(16) ushort_t cE[17 * CE_RS];  // 21760 B
    __shared__ __align__(16) ushort_t cO[17 * CO_RS];  // 23120 B
    __shared__ __align__(16) float c2s[16 * 260];      // 16640 B
    __shared__ __align__(16) float sm2[33 * 68];       // 8976 B
    __shared__ __align__(16) float w1s[384];           // 1536 B
    const int b = blockIdx.x, t = threadIdx.x;
    const float* og = obs + (size_t)b * 4096;

    const int w = t >> 6, L = t & 63, q = L >> 4, ln = L & 15;

    // conv2 B-fragments (same for every wave; L1-resident)
    bf16x8 Bv[9];
    #pragma unroll
    for (int tap = 0; tap < 9; tap++)
        Bv[tap] = *reinterpret_cast<const bf16x8*>(&Btg[(tap * 16 + ln) * 32 + q * 8]);

    // zero: cE buffer row 0 (c1 row -1), cO row 0, cO pos0 (col -1) rows 1..16
    {
        uint_t* zE = (uint_t*)cE;
        uint_t* zO = (uint_t*)cO;
        for (int i = t; i < CE_RS / 2; i += 512) zE[i] = 0;
        for (int i = t; i < CO_RS / 2; i += 512) zO[i] = 0;
        if (t < 320) {
            int row = (t / 20) + 1, d = t % 20;
            zO[row * (CO_RS / 2) + d] = 0;
        }
    }
    if (t < 96) ((float4*)w1s)[t] = ((const float4*)w1p)[t];
    if (t < 33) sm2[t * 68 + 3] = 0.f;  // img col -1 = 0, all staged rows

    // stage obs rows 32ph-1 .. 32ph+31 -> sm2 rows 0..32 (img col j at 4+j)
    auto stage_obs = [&](int ph) {
        for (int i = t; i < 33 * 16; i += 512) {
            int row = i >> 4, c4 = i & 15;
            int orow = 32 * ph - 1 + row;
            float4 v = float4{0.f, 0.f, 0.f, 0.f};
            if (orow >= 0) v = ((const float4*)(og + (size_t)orow * 64))[c4];
            *(float4*)&sm2[row * 68 + 4 + 4 * c4] = v;
        }
    };

    // conv1 phase: thread (r = t>>5, c = t&31) computes c1 row 16ph+r, col c,
    // all 32 ic.  Buffer row = (c1row+1) mod 17 = ph ? r : r+1.
    auto conv1_phase = [&](int ph) {
        const int r = t >> 5, c = t & 31;
        const int brow = ph ? r : (r + 1);
        float P[3][3];  // P[d][dx] = obs[2*(16ph+r)-1+d][2c-1+dx]
        #pragma unroll
        for (int d = 0; d < 3; d++) {
            const float* sr = &sm2[(2 * r + d) * 68 + 2 * c + 2];
            float2 u = *(const float2*)sr;
            float2 v = *(const float2*)(sr + 2);
            P[d][0] = u.y; P[d][1] = v.x; P[d][2] = v.y;
        }
        ushort_t* dst = (c & 1) ? &cO[brow * CO_RS + ((c + 1) >> 1) * 40]
                                : &cE[brow * CE_RS + (c >> 1) * 40];
        #pragma unroll
        for (int round = 0; round < 4; round++) {
            uint_t pk[4];
            #pragma unroll
            for (int icl = 0; icl < 8; icl++) {
                const float* qw = &w1s[(round * 8 + icl) * 12];
                float4 qa = *(const float4*)qw;
                float4 qb = *(const float4*)(qw + 4);
                float s = qw[9];
                s += qa.x * P[0][0] + qa.y * P[0][1] + qa.z * P[0][2];
                s += qa.w * P[1][0] + qb.x * P[1][1] + qb.y * P[1][2];
                s += qb.z * P[2][0] + qb.w * P[2][1] + qw[8] * P[2][2];
                s = fmaxf(s, 0.f);
                ushort_t uu = f2bf(s);
                if (icl & 1) pk[icl >> 1] |= ((uint_t)uu) << 16;
                else         pk[icl >> 1] = uu;
            }
            *(uint4*)(dst + round * 8) = uint4{pk[0], pk[1], pk[2], pk[3]};
        }
    };

    // conv2 phase: wave w -> output row y = 8ph+w; 9 tap-MFMAs; epilogue to c2s
    auto conv2_phase = [&](int ph) {
        const int y = 8 * ph + w;
        f32x4v C = {0.f, 0.f, 0.f, 0.f};
        #pragma unroll
        for (int dy = 0; dy < 3; dy++) {
            int br = 2 * y + dy;          // (c1row+1); c1row = 2y-1+dy
            if (br >= 17) br -= 17;
            bf16x8 a0 = *reinterpret_cast<const bf16x8*>(&cO[br * CO_RS + ln * 40 + q * 8]);        // dx=0: col 2m-1
            bf16x8 a1 = *reinterpret_cast<const bf16x8*>(&cE[br * CE_RS + ln * 40 + q * 8]);        // dx=1: col 2m
            bf16x8 a2 = *reinterpret_cast<const bf16x8*>(&cO[br * CO_RS + (ln + 1) * 40 + q * 8]);  // dx=2: col 2m+1
            C = __builtin_amdgcn_mfma_f32_16x16x32_bf16(a0, Bv[dy * 3 + 0], C, 0, 0, 0);
            C = __builtin_amdgcn_mfma_f32_16x16x32_bf16(a1, Bv[dy * 3 + 1], C, 0, 0, 0);
            C = __builtin_amdgcn_mfma_f32_16x16x32_bf16(a2, Bv[dy * 3 + 2], C, 0, 0, 0);
        }
        float bb2 = b2[ln];
        float4 o;
        o.x = fmaxf(C[0] + bb2, 0.f);
        o.y = fmaxf(C[1] + bb2, 0.f);
        o.z = fmaxf(C[2] + bb2, 0.f);
        o.w = fmaxf(C[3] + bb2, 0.f);
        *(float4*)&c2s[ln * 260 + y * 16 + q * 4] = o;  // oc=ln, x=q*4+r
    };

    stage_obs(0);
    __syncthreads();
    conv1_phase(0);            // writes buffer rows 1..16 (c1 rows 0..15)
    __syncthreads();
    stage_obs(1);              // global loads overlap phase-0 MFMAs
    conv2_phase(0);            // reads rows 0..16; c2 rows 0..7
    __syncthreads();
    conv1_phase(1);            // writes buffer rows 0..15 (c1 rows 16..31); row 16 (c1 15) preserved
    __syncthreads();
    conv2_phase(1);            // c2 rows 8..15
    __syncthreads();

    // pool 3x3 stride 3 -> obs_emb (b, 400)
    if (t < 400) {
        int c = t / 25, rem = t % 25, py = rem / 5, px = rem % 5;
        float s = 0.f;
        #pragma unroll
        for (int dy = 0; dy < 3; dy++)
            #pragma unroll
            for (int dx = 0; dx < 3; dx++)
                s += c2s[c * 260 + (3 * py + dy) * 16 + 3 * px + dx];
        obs_emb[(size_t)b * 400 + t] = s * (1.f / 9.f);
    }
}

// ---------------------------------------------------------------------------
// obs_part (bf16) = obs_emb (B x 400) @ W_obs.T -> (B x 1024)
// ---------------------------------------------------------------------------
__global__ __launch_bounds__(512) void obs_gemm(
    const float* __restrict__ A, const float* __restrict__ Wt,
    ushort_t* __restrict__ outp)
{
    __shared__ float as_t[400][20];
    __shared__ float Ws[8 * 1024];
    const int t = threadIdx.x;
    const int u = t & 255;
    const int mh = t >> 8;
    const int b0 = blockIdx.x * 16;
    float acc[8][4];
    #pragma unroll
    for (int m = 0; m < 8; m++)
        #pragma unroll
        for (int g = 0; g < 4; g++) acc[m][g] = 0.f;

    for (int i = t; i < 16 * 400; i += 512) {
        int r = i / 400, c = i % 400;
        as_t[c][r] = A[(size_t)(b0 + r) * 400 + c];
    }
    for (int kt = 0; kt < 50; kt++) {
        __syncthreads();
        int k0 = kt * 8;
        #pragma unroll
        for (int i = 0; i < 4; i++) {
            int f = t + i * 512;
            int rr = f >> 8, cc = f & 255;
            ((float4*)Ws)[f] = ((const float4*)(Wt + (size_t)(k0 + rr) * 1024))[cc];
        }
        __syncthreads();
        #pragma unroll
        for (int kk = 0; kk < 8; kk++) {
            float w0 = Ws[kk * 1024 + u];
            float w1 = Ws[kk * 1024 + u + 256];
            float w2 = Ws[kk * 1024 + u + 512];
            float w3 = Ws[kk * 1024 + u + 768];
            const float4* hp = (const float4*)&as_t[k0 + kk][mh * 8];
            float4 ha = hp[0], hb = hp[1];
            float hv[8] = {ha.x, ha.y, ha.z, ha.w, hb.x, hb.y, hb.z, hb.w};
            #pragma unroll
            for (int m = 0; m < 8; m++) {
                acc[m][0] += hv[m] * w0;
                acc[m][1] += hv[m] * w1;
                acc[m][2] += hv[m] * w2;
                acc[m][3] += hv[m] * w3;
            }
        }
    }
    #pragma unroll
    for (int m = 0; m < 8; m++) {
        size_t row = b0 + mh * 8 + m;
        #pragma unroll
        for (int g = 0; g < 4; g++)
            outp[row * 1024 + u + 256 * g] = f2bf(acc[m][g]);
    }
}

// ---------------------------------------------------------------------------
// step0 elementwise: h=c=0 -> c0 (fp32), hb0 (bf16). pre = obs_part + bias0.
// ---------------------------------------------------------------------------
__global__ __launch_bounds__(256) void step0_ew(
    const ushort_t* __restrict__ obs_part, const float* __restrict__ bias_s,
    float* __restrict__ c_out, ushort_t* __restrict__ hb_out)
{
    const int R = blockIdx.x, u = threadIdx.x;
    float pre[4];
    #pragma unroll
    for (int g = 0; g < 4; g++)
        pre[g] = bf2f(obs_part[(size_t)R * 1024 + g * 256 + u]) + bias_s[g * 256 + u];
    float c2 = sigf(pre[0]) * tanh_fast(pre[2]);
    float hv = sigf(pre[3]) * tanh_fast(c2);
    c_out[(size_t)R * 256 + u] = c2;
    hb_out[(size_t)R * 256 + u] = f2bf(hv);
}

// ---------------------------------------------------------------------------
// MFMA LSTM step (as R6, passing).
// ---------------------------------------------------------------------------
template <int SAMP, int HEAD_N>
__global__ __launch_bounds__(512, 4) void lstm_mfma(
    const ushort_t* __restrict__ hb_in, const float* __restrict__ c_in,
    ushort_t* __restrict__ hb_out, float* __restrict__ c_out,
    const ushort_t* __restrict__ obs_part, const float* __restrict__ bias_s,
    const float* __restrict__ samp_rows, const int* __restrict__ samp_idx,
    const float* __restrict__ rp0_emb, const float* __restrict__ WsampT,
    const ushort_t* __restrict__ Wb,
    const float* __restrict__ head_w, const float* __restrict__ head_b,
    float* __restrict__ out, int out_off)
{
    __shared__ ushort_t hAs[64 * 264];   // 33792 B, row stride 528 B
    __shared__ float hws[3 * 256];       // head weights
    __shared__ float red[64 * 8 * 3];    // head partials
    const int t = threadIdx.x;
    const int bm = blockIdx.x & 63, bu = blockIdx.x >> 6;
    const int b0 = bm * 64;

    #pragma unroll
    for (int i = 0; i < 4; i++) {
        int idx = t + i * 512, row = idx >> 5, c = idx & 31;
        float4 v = reinterpret_cast<const float4*>(hb_in + (size_t)(b0 + row) * 256)[c];
        *reinterpret_cast<float4*>(&hAs[row * 264 + c * 8]) = v;
    }
    if (HEAD_N > 0 && bu == 0)
        for (int i = t; i < HEAD_N * 256; i += 512) hws[i] = head_w[i];
    __syncthreads();

    const int w = t >> 6, L = t & 63, q = L >> 4, ln = L & 15;
    const int m0 = (w & 3) * 16;
    const int U = bu * 32 + (w >> 2) * 16;
    const int unit = U + ln;

    bf16x8 a[8];
    #pragma unroll
    for (int kk = 0; kk < 8; kk++)
        a[kk] = *reinterpret_cast<const bf16x8*>(&hAs[(m0 + ln) * 264 + kk * 32 + q * 8]);

    f32x4v acc[4];
    #pragma unroll
    for (int g = 0; g < 4; g++) {
        f32x4v z = {0.f, 0.f, 0.f, 0.f};
        const ushort_t* wrow = Wb + (size_t)(g * 256 + unit) * 256 + q * 8;
        #pragma unroll
        for (int kk = 0; kk < 8; kk++) {
            bf16x8 bv = *reinterpret_cast<const bf16x8*>(wrow + kk * 32);
            z = __builtin_amdgcn_mfma_f32_16x16x32_bf16(a[kk], bv, z, 0, 0, 0);
        }
        acc[g] = z;
    }

    #pragma unroll
    for (int r = 0; r < 4; r++) {
        const int R = b0 + m0 + q * 4 + r;
        float pre[4];
        #pragma unroll
        for (int g = 0; g < 4; g++) {
            int col = g * 256 + unit;
            pre[g] = acc[g][r] + bf2f(obs_part[(size_t)R * 1024 + col]) + bias_s[col];
        }
        if (SAMP == 1) {
            int si = samp_idx[R];
            #pragma unroll
            for (int g = 0; g < 4; g++) pre[g] += samp_rows[si * 1024 + g * 256 + unit];
        }
        if (SAMP == 2) {
            #pragma unroll
            for (int k = 0; k < 16; k++) {
                float e = rp0_emb[(size_t)R * 16 + k];
                #pragma unroll
                for (int g = 0; g < 4; g++) pre[g] += e * WsampT[k * 1024 + g * 256 + unit];
            }
        }
        float ci = c_in[(size_t)R * 256 + unit];
        float c2 = sigf(pre[1]) * ci + sigf(pre[0]) * tanh_fast(pre[2]);
        float hv = sigf(pre[3]) * tanh_fast(c2);
        c_out[(size_t)R * 256 + unit] = c2;
        hb_out[(size_t)R * 256 + unit] = f2bf(hv);
    }

    if (HEAD_N > 0 && bu == 0) {
        const int row = t >> 3, seg = t & 7;
        float part[3] = {0.f, 0.f, 0.f};
        #pragma unroll
        for (int j = 0; j < 4; j++) {
            uint4 v = *reinterpret_cast<const uint4*>(&hAs[row * 264 + seg * 32 + j * 8]);
            uint_t dw[4] = {v.x, v.y, v.z, v.w};
            #pragma unroll
            for (int d = 0; d < 4; d++) {
                float f0 = __uint_as_float(dw[d] << 16);
                float f1 = __uint_as_float(dw[d] & 0xffff0000u);
                int k = seg * 32 + j * 8 + d * 2;
                #pragma unroll
                for (int n = 0; n < HEAD_N; n++)
                    part[n] += f0 * hws[n * 256 + k] + f1 * hws[n * 256 + k + 1];
            }
        }
        #pragma unroll
        for (int n = 0; n < HEAD_N; n++) red[(row * 8 + seg) * 3 + n] = part[n];
        __syncthreads();
        if (t < 64) {
            #pragma unroll
            for (int n = 0; n < HEAD_N; n++) {
                float s = head_b[n];
                #pragma unroll
                for (int p = 0; p < 8; p++) s += red[(t * 8 + p) * 3 + n];
                out[(size_t)(b0 + t) * OUT_W + out_off + n] = s;
            }
        }
    }
}

// ---------------------------------------------------------------------------
// rp head: out[:, off:off+2] = rp[:, :2] + exp(rp[:, 2:]) * eps, from hb.
// ---------------------------------------------------------------------------
__global__ __launch_bounds__(256) void rp_head(
    const ushort_t* __restrict__ hb, const float* __restrict__ head_w,
    const float* __restrict__ head_b, const float* __restrict__ eps,
    float* __restrict__ out, int out_off, float* __restrict__ rp_store)
{
    __shared__ float hw[1024];
    __shared__ float red[64 * 4 * 4];
    const int t = threadIdx.x;
    const int b0 = blockIdx.x * 64;
    for (int i = t; i < 1024; i += 256) hw[i] = head_w[i];
    __syncthreads();
    const int r = t >> 2, p = t & 3;
    {
        const int R = b0 + r;
        float part[4] = {0.f, 0.f, 0.f, 0.f};
        const ushort_t* hr = hb + (size_t)R * 256 + p * 64;
        #pragma unroll
        for (int j = 0; j < 8; j++) {
            uint4 v = *reinterpret_cast<const uint4*>(hr + j * 8);
            uint_t dw[4] = {v.x, v.y, v.z, v.w};
            #pragma unroll
            for (int d = 0; d < 4; d++) {
                float f0 = __uint_as_float(dw[d] << 16);
                float f1 = __uint_as_float(dw[d] & 0xffff0000u);
                int k = p * 64 + j * 8 + d * 2;
                #pragma unroll
                for (int n = 0; n < 4; n++)
                    part[n] += f0 * hw[n * 256 + k] + f1 * hw[n * 256 + k + 1];
            }
        }
        #pragma unroll
        for (int n = 0; n < 4; n++) red[(r * 4 + p) * 4 + n] = part[n];
    }
    __syncthreads();
    if (t < 64) {
        const int R = b0 + t;
        float s[4];
        #pragma unroll
        for (int n = 0; n < 4; n++) {
            float v = head_b[n];
            #pragma unroll
            for (int p2 = 0; p2 < 4; p2++) v += red[(t * 4 + p2) * 4 + n];
            s[n] = v;
        }
        float v0 = s[0] + __expf(s[2]) * eps[(size_t)R * 2 + 0];
        float v1 = s[1] + __expf(s[3]) * eps[(size_t)R * 2 + 1];
        out[(size_t)R * OUT_W + out_off + 0] = v0;
        out[(size_t)R * OUT_W + out_off + 1] = v1;
        if (rp_store) {
            rp_store[(size_t)R * 2 + 0] = v0;
            rp_store[(size_t)R * 2 + 1] = v1;
        }
    }
}

// ---------------------------------------------------------------------------
// MLP: rp0 (B x 2) -> 100 -> 100 -> rp0_emb (B x 16)
// ---------------------------------------------------------------------------
__global__ __launch_bounds__(128) void mlp_kernel(
    const float* __restrict__ rp0, const float* __restrict__ w1,
    const float* __restrict__ b1, const float* __restrict__ w2t,
    const float* __restrict__ b2, const float* __restrict__ w3t,
    const float* __restrict__ b3, float* __restrict__ emb)
{
    __shared__ float z1[100], z2[100];
    int row = blockIdx.x, t = threadIdx.x;
    float r0 = rp0[(size_t)row * 2], r1 = rp0[(size_t)row * 2 + 1];
    if (t < 100) z1[t] = tanh_fast(b1[t] + w1[t * 2] * r0 + w1[t * 2 + 1] * r1);
    __syncthreads();
    if (t < 100) {
        float s = b2[t];
        for (int k = 0; k < 100; k++) s += w2t[k * 100 + t] * z1[k];
        z2[t] = tanh_fast(s);
    }
    __syncthreads();
    if (t < 16) {
        float s = b3[t];
        for (int k = 0; k < 100; k++) s += w3t[k * 16 + t] * z2[k];
        emb[(size_t)row * 16 + t] = s;
    }
}

// ---------------------------------------------------------------------------
extern "C" void kernel_launch(void* const* d_in, const int* in_sizes, int n_in,
                              void* d_out, int out_size, void* d_ws, size_t ws_size,
                              hipStream_t stream)
{
    const float* obs        = (const float*)d_in[0];
    const int*   program_id = (const int*)d_in[1];
    const int*   shape_id   = (const int*)d_in[2];
    const int*   shape_id_0 = (const int*)d_in[3];
    const int*   shape_id_1 = (const int*)d_in[4];
    const float* eps_rp     = (const float*)d_in[5];
    const float* eps_rp0    = (const float*)d_in[6];
    const float* eps_rp1    = (const float*)d_in[7];
    const float* conv1_w    = (const float*)d_in[8];
    const float* conv1_b    = (const float*)d_in[9];
    const float* conv2_w    = (const float*)d_in[10];
    const float* conv2_b    = (const float*)d_in[11];
    const float* mlp_w1     = (const float*)d_in[12];
    const float* mlp_b1     = (const float*)d_in[13];
    const float* mlp_w2     = (const float*)d_in[14];
    const float* mlp_b2     = (const float*)d_in[15];
    const float* mlp_w3     = (const float*)d_in[16];
    const float* mlp_b3     = (const float*)d_in[17];
    const float* W_ih       = (const float*)d_in[18];
    const float* b_ih       = (const float*)d_in[19];
    const float* W_hh       = (const float*)d_in[20];
    const float* b_hh       = (const float*)d_in[21];
    const float* addr_emb   = (const float*)d_in[22];
    const float* pid_emb    = (const float*)d_in[23];
    const float* sid_emb    = (const float*)d_in[24];
    const float* pid_ext_w  = (const float*)d_in[25];
    const float* pid_ext_b  = (const float*)d_in[26];
    const float* sid_ext_w  = (const float*)d_in[27];
    const float* sid_ext_b  = (const float*)d_in[28];
    const float* rp_ext_w   = (const float*)d_in[29];
    const float* rp_ext_b   = (const float*)d_in[30];
    float* out = (float*)d_out;

    // workspace layout (float slots, 16B-aligned chunks)
    float* ws = (float*)d_ws;
    size_t off = 0;
    float* W_ih_T   = ws + off; off += 432 * 1024;              // fp32
    ushort_t* Wb    = (ushort_t*)(ws + off); off += 131072;     // bf16 1024x256
    float* bias_all = ws + off; off += 7 * 1024;
    float* pid_rows = ws + off; off += 3 * 1024;
    float* sid_rows = ws + off; off += 2 * 1024;
    float* obs_emb  = ws + off; off += (size_t)BATCH * 400;
    ushort_t* obs_part = (ushort_t*)(ws + off); off += (size_t)BATCH * 512;  // bf16 Bx1024
    ushort_t* hb0 = (ushort_t*)(ws + off); off += (size_t)BATCH * 128;      // bf16 Bx256
    ushort_t* hbA = (ushort_t*)(ws + off); off += (size_t)BATCH * 128;
    ushort_t* hbB = (ushort_t*)(ws + off); off += (size_t)BATCH * 128;
    ushort_t* hbC = (ushort_t*)(ws + off); off += (size_t)BATCH * 128;
    float* c0 = ws + off; off += (size_t)BATCH * 256;
    float* cA = ws + off; off += (size_t)BATCH * 256;
    float* cB = ws + off; off += (size_t)BATCH * 256;
    float* cC = ws + off; off += (size_t)BATCH * 256;
    float* cD = ws + off; off += (size_t)BATCH * 256;   // dump for terminal c
    float* rp0      = ws + off; off += (size_t)BATCH * 2;
    float* rp0_emb  = ws + off; off += (size_t)BATCH * 16;
    float* w2t = ws + off; off += 10000;
    float* w3t = ws + off; off += 1600;
    float* w1p = ws + off; off += 384;
    ushort_t* Btg = (ushort_t*)(ws + off); off += 2304;  // 4608 bf16
    float* WsampT = W_ih_T + (size_t)400 * 1024;  // rows 400..415 of W_ih_T (fp32)

    prep_kernel<<<124, 256, 0, stream>>>(W_ih, W_hh, b_ih, b_hh, addr_emb,
                                         pid_emb, sid_emb, mlp_w2, mlp_w3,
                                         conv1_w, conv1_b, conv2_w,
                                         W_ih_T, Wb, bias_all, pid_rows,
                                         sid_rows, w2t, w3t, w1p, Btg);
    conv_kernel<<<BATCH, 512, 0, stream>>>(obs, w1p, Btg, conv2_b, obs_emb);
    obs_gemm<<<BATCH / 16, 512, 0, stream>>>(obs_emb, W_ih_T, obs_part);

    // step0 (aid 0): h=c=0 -> hb0, c0 (pid head on h0 folded into step1)
    step0_ew<<<BATCH, 256, 0, stream>>>(obs_part, bias_all + 0 * 1024, c0, hb0);

    // step1 (aid 1): hb0,c0 -> hbA,cA; samp pid; head = pid_logits(3) on h0 -> cols 0..2
    lstm_mfma<1, 3><<<512, 512, 0, stream>>>(
        hb0, c0, hbA, cA, obs_part, bias_all + 1 * 1024,
        pid_rows, program_id, nullptr, nullptr, Wb,
        pid_ext_w, pid_ext_b, out, 0);
    // step2 (aid 4): hbA,cA -> hbB,cD; samp sid[shape_id]; head = sid(2) on h1 -> cols 3..4
    lstm_mfma<1, 2><<<512, 512, 0, stream>>>(
        hbA, cA, hbB, cD, obs_part, bias_all + 2 * 1024,
        sid_rows, shape_id, nullptr, nullptr, Wb,
        sid_ext_w, sid_ext_b, out, 3);
    // rp_b0 head on h2 (hbB) -> cols 5..6
    rp_head<<<64, 256, 0, stream>>>(hbB, rp_ext_w, rp_ext_b, eps_rp, out, 5, nullptr);
    // step1b (aid 2): hb0,c0 -> hbA,cA; samp pid; no head
    lstm_mfma<1, 0><<<512, 512, 0, stream>>>(
        hb0, c0, hbA, cA, obs_part, bias_all + 3 * 1024,
        pid_rows, program_id, nullptr, nullptr, Wb,
        nullptr, nullptr, out, 0);
    // step2b (aid 3): hbA,cA -> hbB,cB; samp sid[shape_id_0]; head = sid0(2) on h1b -> cols 7..8
    lstm_mfma<1, 2><<<512, 512, 0, stream>>>(
        hbA, cA, hbB, cB, obs_part, bias_all + 4 * 1024,
        sid_rows, shape_id_0, nullptr, nullptr, Wb,
        sid_ext_w, sid_ext_b, out, 7);
    // step3b (aid 5): hbB,cB -> hbC,cC; samp sid[shape_id_1]; head = sid1(2) on h2b -> cols 9..10
    lstm_mfma<1, 2><<<512, 512, 0, stream>>>(
        hbB, cB, hbC, cC, obs_part, bias_all + 5 * 1024,
        sid_rows, shape_id_1, nullptr, nullptr, Wb,
        sid_ext_w, sid_ext_b, out, 9);
    // rp0 head on h3b (hbC) -> cols 11..12, store rp0
    rp_head<<<64, 256, 0, stream>>>(hbC, rp_ext_w, rp_ext_b, eps_rp0, out, 11, rp0);
    mlp_kernel<<<BATCH, 128, 0, stream>>>(rp0, mlp_w1, mlp_b1, w2t, mlp_b2,
                                          w3t, mlp_b3, rp0_emb);
    // step4b (aid 6): hbC,cC -> hbB,cD; samp = rp0_emb @ WsampT; no head
    lstm_mfma<2, 0><<<512, 512, 0, stream>>>(
        hbC, cC, hbB, cD, obs_part, bias_all + 6 * 1024,
        nullptr, nullptr, rp0_emb, WsampT, Wb,
        nullptr, nullptr, out, 0);
    // rp1 head on h4b (hbB) -> cols 13..14
    rp_head<<<64, 256, 0, stream>>>(hbB, rp_ext_w, rp_ext_b, eps_rp1, out, 13, nullptr);
}

// Round 2
// 494.420 us; speedup vs baseline: 1.0990x; 1.0857x over previous
//
#include <hip/hip_runtime.h>
#include <hip/hip_bf16.h>
#include <math.h>

#define BATCH 4096
#define HID 256
#define OUT_W 15

typedef unsigned short ushort_t;
typedef unsigned int uint_t;

using bf16x8 = __attribute__((ext_vector_type(8))) short;
using f32x4v = __attribute__((ext_vector_type(4))) float;

__device__ __forceinline__ float sigf(float x) { return 1.0f / (1.0f + __expf(-x)); }
__device__ __forceinline__ float tanh_fast(float x) { return 1.0f - 2.0f / (__expf(2.0f * x) + 1.0f); }
__device__ __forceinline__ float bf2f(ushort_t u) { return __uint_as_float(((uint_t)u) << 16); }
__device__ __forceinline__ ushort_t f2bf(float x) {
    uint_t b = __float_as_uint(x);
    return (ushort_t)((b + 0x7fffu + ((b >> 16) & 1u)) >> 16);
}

// ---------------------------------------------------------------------------
// Prep: W_ih transpose, per-step biases, samp tables, mlp transposes,
// packed conv1 weights w1p[ic][12], conv2 B-fragments Btg[tap][oc][ic] bf16,
// W_hh -> bf16 [n][k].
// ---------------------------------------------------------------------------
__global__ __launch_bounds__(256) void prep_kernel(
    const float* __restrict__ W_ih, const float* __restrict__ W_hh,
    const float* __restrict__ b_ih, const float* __restrict__ b_hh,
    const float* __restrict__ addr_emb, const float* __restrict__ pid_emb,
    const float* __restrict__ sid_emb,
    const float* __restrict__ mlp_w2, const float* __restrict__ mlp_w3,
    const float* __restrict__ conv1_w, const float* __restrict__ conv1_b,
    const float* __restrict__ conv2_w,
    float* __restrict__ W_ih_T, ushort_t* __restrict__ Wb,
    float* __restrict__ bias_all, float* __restrict__ pid_rows,
    float* __restrict__ sid_rows, float* __restrict__ w2t, float* __restrict__ w3t,
    float* __restrict__ w1p, ushort_t* __restrict__ Btg)
{
    int blk = blockIdx.x, t = threadIdx.x;
    if (blk < 112) {
        // W_ih (1024x432) -> W_ih_T (432x1024)
        __shared__ float tile[64][65];
        int j0 = (blk & 15) * 64;
        int k0 = (blk >> 4) * 64;
        for (int i = t; i < 4096; i += 256) {
            int r = i >> 6, c = i & 63;
            int k = k0 + c;
            tile[r][c] = (k < 432) ? W_ih[(size_t)(j0 + r) * 432 + k] : 0.f;
        }
        __syncthreads();
        for (int i = t; i < 4096; i += 256) {
            int r = i >> 6, c = i & 63;
            int k = k0 + r;
            if (k < 432) W_ih_T[(size_t)k * 1024 + j0 + c] = tile[c][r];
        }
    } else if (blk == 112) {
        const int aids[7] = {0, 1, 4, 2, 3, 5, 6};
        for (int s = 0; s < 7; s++) {
            int aid = aids[s];
            for (int j = t; j < 1024; j += 256) {
                float v = b_ih[j] + b_hh[j];
                #pragma unroll
                for (int k = 0; k < 16; k++)
                    v += addr_emb[aid * 16 + k] * W_ih[(size_t)j * 432 + 416 + k];
                bias_all[s * 1024 + j] = v;
            }
        }
    } else if (blk == 113) {
        for (int p = 0; p < 3; p++)
            for (int j = t; j < 1024; j += 256) {
                float v = 0.f;
                #pragma unroll
                for (int k = 0; k < 16; k++)
                    v += pid_emb[p * 16 + k] * W_ih[(size_t)j * 432 + 400 + k];
                pid_rows[p * 1024 + j] = v;
            }
        for (int p = 0; p < 2; p++)
            for (int j = t; j < 1024; j += 256) {
                float v = 0.f;
                #pragma unroll
                for (int k = 0; k < 16; k++)
                    v += sid_emb[p * 16 + k] * W_ih[(size_t)j * 432 + 400 + k];
                sid_rows[p * 1024 + j] = v;
            }
    } else if (blk == 114) {
        for (int i = t; i < 10000; i += 256) {
            int o = i / 100, k = i % 100;
            w2t[k * 100 + o] = mlp_w2[i];
        }
        for (int i = t; i < 1600; i += 256) {
            int o = i / 100, k = i % 100;
            w3t[k * 16 + o] = mlp_w3[i];
        }
    } else if (blk == 115) {
        for (int i = t; i < 384; i += 256) {
            int ic = i / 12, k = i % 12;
            float v = 0.f;
            if (k < 9) v = conv1_w[ic * 9 + k];
            else if (k == 9) v = conv1_b[ic];
            w1p[i] = v;
        }
        // Btg[(tap*16 + oc)*32 + ic] = conv2_w[(oc*32+ic)*9 + tap]
        for (int i = t; i < 4608; i += 256) {
            int tap = i >> 9;
            int rem = i & 511;
            int oc = rem >> 5, ic = rem & 31;
            Btg[i] = f2bf(conv2_w[(size_t)(oc * 32 + ic) * 9 + tap]);
        }
    } else {
        // W_hh (1024x256) fp32 -> bf16, same [n][k] layout
        int seg = blk - 116;  // 0..7
        for (int i = seg * 32768 + t; i < (seg + 1) * 32768; i += 256)
            Wb[i] = f2bf(W_hh[i]);
    }
}

// ---------------------------------------------------------------------------
// Conv encoder v4: two half-image phases over a 17-row ring buffer.
//   512 threads, LDS ~70 KB -> 2 blocks/CU (16 waves/CU).
//   conv1 thread decomposition (r = t>>5, g = (t>>2)&7, icq = t&3):
//     row 16ph+r, cols 4g..4g+3, ics 8icq..8icq+7 -- obs patch Pt[3][12]
//     loaded ONCE per phase (9 ds_read_b128), weights register-resident in
//     two 4-ic halves (6 ds_reads/phase vs ~96 in v3: kills the LDS-issue
//     bottleneck of broadcast per-position weight re-reads).
//   conv2: output rows 8ph..8ph+7, 1 row/wave, 9 tap-MFMAs (unchanged).
//   Ring: buffer row = (c1row+1) mod 17 -> halo row (c1 row 15) free.
//   cE: even cols 0..30 (16 pos), cO: odd cols -1..31 (17 pos), pos stride
//   40 ushorts (80 B) -> conflict-free A-frag ds_read_b128.
// ---------------------------------------------------------------------------
#define CE_RS 640   // cE row stride in ushorts (16 pos * 40)
#define CO_RS 680   // cO row stride in ushorts (17 pos * 40)
__global__ __launch_bounds__(512, 4) void conv_kernel(
    const float* __restrict__ obs, const float* __restrict__ w1p,
    const ushort_t* __restrict__ Btg, const float* __restrict__ b2,
    float* __restrict__ obs_emb)
{
    __shared__ __align__(16) ushort_t cE[17 * CE_RS];  // 21760 B
    __shared__ __align__(16) ushort_t cO[17 * CO_RS];  // 23120 B
    __shared__ __align__(16) float c2s[16 * 260];      // 16640 B
    __shared__ __align__(16) float sm2[33 * 68];       // 8976 B
    __shared__ __align__(16) float w1s[384];           // 1536 B
    const int b = blockIdx.x, t = threadIdx.x;
    const float* og = obs + (size_t)b * 4096;

    const int w = t >> 6, L = t & 63, q = L >> 4, ln = L & 15;

    // conv2 B-fragments (same for every wave; L1-resident)
    bf16x8 Bv[9];
    #pragma unroll
    for (int tap = 0; tap < 9; tap++)
        Bv[tap] = *reinterpret_cast<const bf16x8*>(&Btg[(tap * 16 + ln) * 32 + q * 8]);

    // zero: cE buffer row 0 (c1 row -1), cO row 0, cO pos0 (col -1) rows 1..16
    {
        uint_t* zE = (uint_t*)cE;
        uint_t* zO = (uint_t*)cO;
        for (int i = t; i < CE_RS / 2; i += 512) zE[i] = 0;
        for (int i = t; i < CO_RS / 2; i += 512) zO[i] = 0;
        if (t < 320) {
            int row = (t / 20) + 1, d = t % 20;
            zO[row * (CO_RS / 2) + d] = 0;
        }
    }
    if (t < 96) ((float4*)w1s)[t] = ((const float4*)w1p)[t];
    if (t < 33) sm2[t * 68 + 3] = 0.f;  // img col -1 = 0, all staged rows

    // stage obs rows 32ph-1 .. 32ph+31 -> sm2 rows 0..32 (img col j at 4+j)
    auto stage_obs = [&](int ph) {
        for (int i = t; i < 33 * 16; i += 512) {
            int row = i >> 4, c4 = i & 15;
            int orow = 32 * ph - 1 + row;
            float4 v = float4{0.f, 0.f, 0.f, 0.f};
            if (orow >= 0) v = ((const float4*)(og + (size_t)orow * 64))[c4];
            *(float4*)&sm2[row * 68 + 4 + 4 * c4] = v;
        }
    };

    // conv1 phase: thread (r = t>>5, g = (t>>2)&7, icq = t&3) computes
    // c1 row 16ph+r, cols 4g..4g+3, ics 8icq..8icq+7.
    // Buffer row = (c1row+1) mod 17 = ph ? r : r+1.
    auto conv1_phase = [&](int ph) {
        const int r = t >> 5, g = (t >> 2) & 7, icq = t & 3;
        const int brow = ph ? r : (r + 1);
        // Pt[d][j] = obs[2*(16ph+r)-1+d][8g-4+j]; needed col for pos p, tap dx
        // is 8g+2p-1+dx -> j = 2p+3+dx (j in 3..11; j<3 lanes dead).
        float Pt[3][12];
        #pragma unroll
        for (int d = 0; d < 3; d++) {
            const float* src = &sm2[(2 * r + d) * 68 + 8 * g];
            #pragma unroll
            for (int j4 = 0; j4 < 3; j4++) {
                float4 v = ((const float4*)src)[j4];
                Pt[d][j4 * 4 + 0] = v.x; Pt[d][j4 * 4 + 1] = v.y;
                Pt[d][j4 * 4 + 2] = v.z; Pt[d][j4 * 4 + 3] = v.w;
            }
        }
        #pragma unroll
        for (int ih = 0; ih < 2; ih++) {
            // 4 ic of register-resident weights
            float W[4][10];
            #pragma unroll
            for (int i = 0; i < 4; i++) {
                const float* qw = &w1s[(icq * 8 + ih * 4 + i) * 12];
                float4 qa = *(const float4*)qw;
                float4 qb = *(const float4*)(qw + 4);
                float2 qc = *(const float2*)(qw + 8);
                W[i][0] = qa.x; W[i][1] = qa.y; W[i][2] = qa.z; W[i][3] = qa.w;
                W[i][4] = qb.x; W[i][5] = qb.y; W[i][6] = qb.z; W[i][7] = qb.w;
                W[i][8] = qc.x; W[i][9] = qc.y;
            }
            #pragma unroll
            for (int p = 0; p < 4; p++) {
                uint_t pk[2];
                #pragma unroll
                for (int i = 0; i < 4; i++) {
                    float s = W[i][9];
                    #pragma unroll
                    for (int d = 0; d < 3; d++)
                        #pragma unroll
                        for (int dx = 0; dx < 3; dx++)
                            s += W[i][d * 3 + dx] * Pt[d][2 * p + 3 + dx];
                    s = fmaxf(s, 0.f);
                    ushort_t uu = f2bf(s);
                    if (i & 1) pk[i >> 1] |= ((uint_t)uu) << 16;
                    else       pk[i >> 1] = uu;
                }
                int c = 4 * g + p;
                ushort_t* dst = (c & 1)
                    ? &cO[brow * CO_RS + ((c + 1) >> 1) * 40 + icq * 8 + ih * 4]
                    : &cE[brow * CE_RS + (c >> 1) * 40 + icq * 8 + ih * 4];
                *(uint2*)dst = uint2{pk[0], pk[1]};
            }
        }
    };

    // conv2 phase: wave w -> output row y = 8ph+w; 9 tap-MFMAs; epilogue to c2s
    auto conv2_phase = [&](int ph) {
        const int y = 8 * ph + w;
        f32x4v C = {0.f, 0.f, 0.f, 0.f};
        #pragma unroll
        for (int dy = 0; dy < 3; dy++) {
            int br = 2 * y + dy;          // (c1row+1); c1row = 2y-1+dy
            if (br >= 17) br -= 17;
            bf16x8 a0 = *reinterpret_cast<const bf16x8*>(&cO[br * CO_RS + ln * 40 + q * 8]);        // dx=0: col 2m-1
            bf16x8 a1 = *reinterpret_cast<const bf16x8*>(&cE[br * CE_RS + ln * 40 + q * 8]);        // dx=1: col 2m
            bf16x8 a2 = *reinterpret_cast<const bf16x8*>(&cO[br * CO_RS + (ln + 1) * 40 + q * 8]);  // dx=2: col 2m+1
            C = __builtin_amdgcn_mfma_f32_16x16x32_bf16(a0, Bv[dy * 3 + 0], C, 0, 0, 0);
            C = __builtin_amdgcn_mfma_f32_16x16x32_bf16(a1, Bv[dy * 3 + 1], C, 0, 0, 0);
            C = __builtin_amdgcn_mfma_f32_16x16x32_bf16(a2, Bv[dy * 3 + 2], C, 0, 0, 0);
        }
        float bb2 = b2[ln];
        float4 o;
        o.x = fmaxf(C[0] + bb2, 0.f);
        o.y = fmaxf(C[1] + bb2, 0.f);
        o.z = fmaxf(C[2] + bb2, 0.f);
        o.w = fmaxf(C[3] + bb2, 0.f);
        *(float4*)&c2s[ln * 260 + y * 16 + q * 4] = o;  // oc=ln, x=q*4+r
    };

    stage_obs(0);
    __syncthreads();
    conv1_phase(0);            // writes buffer rows 1..16 (c1 rows 0..15)
    __syncthreads();
    stage_obs(1);              // global loads overlap phase-0 MFMAs
    conv2_phase(0);            // reads rows 0..16; c2 rows 0..7
    __syncthreads();
    conv1_phase(1);            // writes buffer rows 0..15 (c1 rows 16..31); row 16 (c1 15) preserved
    __syncthreads();
    conv2_phase(1);            // c2 rows 8..15
    __syncthreads();

    // pool 3x3 stride 3 -> obs_emb (b, 400)
    if (t < 400) {
        int c = t / 25, rem = t % 25, py = rem / 5, px = rem % 5;
        float s = 0.f;
        #pragma unroll
        for (int dy = 0; dy < 3; dy++)
            #pragma unroll
            for (int dx = 0; dx < 3; dx++)
                s += c2s[c * 260 + (3 * py + dy) * 16 + 3 * px + dx];
        obs_emb[(size_t)b * 400 + t] = s * (1.f / 9.f);
    }
}

// ---------------------------------------------------------------------------
// obs_part (bf16) = obs_emb (B x 400) @ W_obs.T -> (B x 1024)
// ---------------------------------------------------------------------------
__global__ __launch_bounds__(512) void obs_gemm(
    const float* __restrict__ A, const float* __restrict__ Wt,
    ushort_t* __restrict__ outp)
{
    __shared__ float as_t[400][20];
    __shared__ float Ws[8 * 1024];
    const int t = threadIdx.x;
    const int u = t & 255;
    const int mh = t >> 8;
    const int b0 = blockIdx.x * 16;
    float acc[8][4];
    #pragma unroll
    for (int m = 0; m < 8; m++)
        #pragma unroll
        for (int g = 0; g < 4; g++) acc[m][g] = 0.f;

    for (int i = t; i < 16 * 400; i += 512) {
        int r = i / 400, c = i % 400;
        as_t[c][r] = A[(size_t)(b0 + r) * 400 + c];
    }
    for (int kt = 0; kt < 50; kt++) {
        __syncthreads();
        int k0 = kt * 8;
        #pragma unroll
        for (int i = 0; i < 4; i++) {
            int f = t + i * 512;
            int rr = f >> 8, cc = f & 255;
            ((float4*)Ws)[f] = ((const float4*)(Wt + (size_t)(k0 + rr) * 1024))[cc];
        }
        __syncthreads();
        #pragma unroll
        for (int kk = 0; kk < 8; kk++) {
            float w0 = Ws[kk * 1024 + u];
            float w1 = Ws[kk * 1024 + u + 256];
            float w2 = Ws[kk * 1024 + u + 512];
            float w3 = Ws[kk * 1024 + u + 768];
            const float4* hp = (const float4*)&as_t[k0 + kk][mh * 8];
            float4 ha = hp[0], hb = hp[1];
            float hv[8] = {ha.x, ha.y, ha.z, ha.w, hb.x, hb.y, hb.z, hb.w};
            #pragma unroll
            for (int m = 0; m < 8; m++) {
                acc[m][0] += hv[m] * w0;
                acc[m][1] += hv[m] * w1;
                acc[m][2] += hv[m] * w2;
                acc[m][3] += hv[m] * w3;
            }
        }
    }
    #pragma unroll
    for (int m = 0; m < 8; m++) {
        size_t row = b0 + mh * 8 + m;
        #pragma unroll
        for (int g = 0; g < 4; g++)
            outp[row * 1024 + u + 256 * g] = f2bf(acc[m][g]);
    }
}

// ---------------------------------------------------------------------------
// step0 elementwise: h=c=0 -> c0 (fp32), hb0 (bf16). pre = obs_part + bias0.
// ---------------------------------------------------------------------------
__global__ __launch_bounds__(256) void step0_ew(
    const ushort_t* __restrict__ obs_part, const float* __restrict__ bias_s,
    float* __restrict__ c_out, ushort_t* __restrict__ hb_out)
{
    const int R = blockIdx.x, u = threadIdx.x;
    float pre[4];
    #pragma unroll
    for (int g = 0; g < 4; g++)
        pre[g] = bf2f(obs_part[(size_t)R * 1024 + g * 256 + u]) + bias_s[g * 256 + u];
    float c2 = sigf(pre[0]) * tanh_fast(pre[2]);
    float hv = sigf(pre[3]) * tanh_fast(c2);
    c_out[(size_t)R * 256 + u] = c2;
    hb_out[(size_t)R * 256 + u] = f2bf(hv);
}

// ---------------------------------------------------------------------------
// MFMA LSTM step (as R6, passing).
// ---------------------------------------------------------------------------
template <int SAMP, int HEAD_N>
__global__ __launch_bounds__(512, 4) void lstm_mfma(
    const ushort_t* __restrict__ hb_in, const float* __restrict__ c_in,
    ushort_t* __restrict__ hb_out, float* __restrict__ c_out,
    const ushort_t* __restrict__ obs_part, const float* __restrict__ bias_s,
    const float* __restrict__ samp_rows, const int* __restrict__ samp_idx,
    const float* __restrict__ rp0_emb, const float* __restrict__ WsampT,
    const ushort_t* __restrict__ Wb,
    const float* __restrict__ head_w, const float* __restrict__ head_b,
    float* __restrict__ out, int out_off)
{
    __shared__ ushort_t hAs[64 * 264];   // 33792 B, row stride 528 B
    __shared__ float hws[3 * 256];       // head weights
    __shared__ float red[64 * 8 * 3];    // head partials
    const int t = threadIdx.x;
    const int bm = blockIdx.x & 63, bu = blockIdx.x >> 6;
    const int b0 = bm * 64;

    #pragma unroll
    for (int i = 0; i < 4; i++) {
        int idx = t + i * 512, row = idx >> 5, c = idx & 31;
        float4 v = reinterpret_cast<const float4*>(hb_in + (size_t)(b0 + row) * 256)[c];
        *reinterpret_cast<float4*>(&hAs[row * 264 + c * 8]) = v;
    }
    if (HEAD_N > 0 && bu == 0)
        for (int i = t; i < HEAD_N * 256; i += 512) hws[i] = head_w[i];
    __syncthreads();

    const int w = t >> 6, L = t & 63, q = L >> 4, ln = L & 15;
    const int m0 = (w & 3) * 16;
    const int U = bu * 32 + (w >> 2) * 16;
    const int unit = U + ln;

    bf16x8 a[8];
    #pragma unroll
    for (int kk = 0; kk < 8; kk++)
        a[kk] = *reinterpret_cast<const bf16x8*>(&hAs[(m0 + ln) * 264 + kk * 32 + q * 8]);

    f32x4v acc[4];
    #pragma unroll
    for (int g = 0; g < 4; g++) {
        f32x4v z = {0.f, 0.f, 0.f, 0.f};
        const ushort_t* wrow = Wb + (size_t)(g * 256 + unit) * 256 + q * 8;
        #pragma unroll
        for (int kk = 0; kk < 8; kk++) {
            bf16x8 bv = *reinterpret_cast<const bf16x8*>(wrow + kk * 32);
            z = __builtin_amdgcn_mfma_f32_16x16x32_bf16(a[kk], bv, z, 0, 0, 0);
        }
        acc[g] = z;
    }

    #pragma unroll
    for (int r = 0; r < 4; r++) {
        const int R = b0 + m0 + q * 4 + r;
        float pre[4];
        #pragma unroll
        for (int g = 0; g < 4; g++) {
            int col = g * 256 + unit;
            pre[g] = acc[g][r] + bf2f(obs_part[(size_t)R * 1024 + col]) + bias_s[col];
        }
        if (SAMP == 1) {
            int si = samp_idx[R];
            #pragma unroll
            for (int g = 0; g < 4; g++) pre[g] += samp_rows[si * 1024 + g * 256 + unit];
        }
        if (SAMP == 2) {
            #pragma unroll
            for (int k = 0; k < 16; k++) {
                float e = rp0_emb[(size_t)R * 16 + k];
                #pragma unroll
                for (int g = 0; g < 4; g++) pre[g] += e * WsampT[k * 1024 + g * 256 + unit];
            }
        }
        float ci = c_in[(size_t)R * 256 + unit];
        float c2 = sigf(pre[1]) * ci + sigf(pre[0]) * tanh_fast(pre[2]);
        float hv = sigf(pre[3]) * tanh_fast(c2);
        c_out[(size_t)R * 256 + unit] = c2;
        hb_out[(size_t)R * 256 + unit] = f2bf(hv);
    }

    if (HEAD_N > 0 && bu == 0) {
        const int row = t >> 3, seg = t & 7;
        float part[3] = {0.f, 0.f, 0.f};
        #pragma unroll
        for (int j = 0; j < 4; j++) {
            uint4 v = *reinterpret_cast<const uint4*>(&hAs[row * 264 + seg * 32 + j * 8]);
            uint_t dw[4] = {v.x, v.y, v.z, v.w};
            #pragma unroll
            for (int d = 0; d < 4; d++) {
                float f0 = __uint_as_float(dw[d] << 16);
                float f1 = __uint_as_float(dw[d] & 0xffff0000u);
                int k = seg * 32 + j * 8 + d * 2;
                #pragma unroll
                for (int n = 0; n < HEAD_N; n++)
                    part[n] += f0 * hws[n * 256 + k] + f1 * hws[n * 256 + k + 1];
            }
        }
        #pragma unroll
        for (int n = 0; n < HEAD_N; n++) red[(row * 8 + seg) * 3 + n] = part[n];
        __syncthreads();
        if (t < 64) {
            #pragma unroll
            for (int n = 0; n < HEAD_N; n++) {
                float s = head_b[n];
                #pragma unroll
                for (int p = 0; p < 8; p++) s += red[(t * 8 + p) * 3 + n];
                out[(size_t)(b0 + t) * OUT_W + out_off + n] = s;
            }
        }
    }
}

// ---------------------------------------------------------------------------
// rp head: out[:, off:off+2] = rp[:, :2] + exp(rp[:, 2:]) * eps, from hb.
// ---------------------------------------------------------------------------
__global__ __launch_bounds__(256) void rp_head(
    const ushort_t* __restrict__ hb, const float* __restrict__ head_w,
    const float* __restrict__ head_b, const float* __restrict__ eps,
    float* __restrict__ out, int out_off, float* __restrict__ rp_store)
{
    __shared__ float hw[1024];
    __shared__ float red[64 * 4 * 4];
    const int t = threadIdx.x;
    const int b0 = blockIdx.x * 64;
    for (int i = t; i < 1024; i += 256) hw[i] = head_w[i];
    __syncthreads();
    const int r = t >> 2, p = t & 3;
    {
        const int R = b0 + r;
        float part[4] = {0.f, 0.f, 0.f, 0.f};
        const ushort_t* hr = hb + (size_t)R * 256 + p * 64;
        #pragma unroll
        for (int j = 0; j < 8; j++) {
            uint4 v = *reinterpret_cast<const uint4*>(hr + j * 8);
            uint_t dw[4] = {v.x, v.y, v.z, v.w};
            #pragma unroll
            for (int d = 0; d < 4; d++) {
                float f0 = __uint_as_float(dw[d] << 16);
                float f1 = __uint_as_float(dw[d] & 0xffff0000u);
                int k = p * 64 + j * 8 + d * 2;
                #pragma unroll
                for (int n = 0; n < 4; n++)
                    part[n] += f0 * hw[n * 256 + k] + f1 * hw[n * 256 + k + 1];
            }
        }
        #pragma unroll
        for (int n = 0; n < 4; n++) red[(r * 4 + p) * 4 + n] = part[n];
    }
    __syncthreads();
    if (t < 64) {
        const int R = b0 + t;
        float s[4];
        #pragma unroll
        for (int n = 0; n < 4; n++) {
            float v = head_b[n];
            #pragma unroll
            for (int p2 = 0; p2 < 4; p2++) v += red[(t * 4 + p2) * 4 + n];
            s[n] = v;
        }
        float v0 = s[0] + __expf(s[2]) * eps[(size_t)R * 2 + 0];
        float v1 = s[1] + __expf(s[3]) * eps[(size_t)R * 2 + 1];
        out[(size_t)R * OUT_W + out_off + 0] = v0;
        out[(size_t)R * OUT_W + out_off + 1] = v1;
        if (rp_store) {
            rp_store[(size_t)R * 2 + 0] = v0;
            rp_store[(size_t)R * 2 + 1] = v1;
        }
    }
}

// ---------------------------------------------------------------------------
// MLP: rp0 (B x 2) -> 100 -> 100 -> rp0_emb (B x 16)
// ---------------------------------------------------------------------------
__global__ __launch_bounds__(128) void mlp_kernel(
    const float* __restrict__ rp0, const float* __restrict__ w1,
    const float* __restrict__ b1, const float* __restrict__ w2t,
    const float* __restrict__ b2, const float* __restrict__ w3t,
    const float* __restrict__ b3, float* __restrict__ emb)
{
    __shared__ float z1[100], z2[100];
    int row = blockIdx.x, t = threadIdx.x;
    float r0 = rp0[(size_t)row * 2], r1 = rp0[(size_t)row * 2 + 1];
    if (t < 100) z1[t] = tanh_fast(b1[t] + w1[t * 2] * r0 + w1[t * 2 + 1] * r1);
    __syncthreads();
    if (t < 100) {
        float s = b2[t];
        for (int k = 0; k < 100; k++) s += w2t[k * 100 + t] * z1[k];
        z2[t] = tanh_fast(s);
    }
    __syncthreads();
    if (t < 16) {
        float s = b3[t];
        for (int k = 0; k < 100; k++) s += w3t[k * 16 + t] * z2[k];
        emb[(size_t)row * 16 + t] = s;
    }
}

// ---------------------------------------------------------------------------
extern "C" void kernel_launch(void* const* d_in, const int* in_sizes, int n_in,
                              void* d_out, int out_size, void* d_ws, size_t ws_size,
                              hipStream_t stream)
{
    const float* obs        = (const float*)d_in[0];
    const int*   program_id = (const int*)d_in[1];
    const int*   shape_id   = (const int*)d_in[2];
    const int*   shape_id_0 = (const int*)d_in[3];
    const int*   shape_id_1 = (const int*)d_in[4];
    const float* eps_rp     = (const float*)d_in[5];
    const float* eps_rp0    = (const float*)d_in[6];
    const float* eps_rp1    = (const float*)d_in[7];
    const float* conv1_w    = (const float*)d_in[8];
    const float* conv1_b    = (const float*)d_in[9];
    const float* conv2_w    = (const float*)d_in[10];
    const float* conv2_b    = (const float*)d_in[11];
    const float* mlp_w1     = (const float*)d_in[12];
    const float* mlp_b1     = (const float*)d_in[13];
    const float* mlp_w2     = (const float*)d_in[14];
    const float* mlp_b2     = (const float*)d_in[15];
    const float* mlp_w3     = (const float*)d_in[16];
    const float* mlp_b3     = (const float*)d_in[17];
    const float* W_ih       = (const float*)d_in[18];
    const float* b_ih       = (const float*)d_in[19];
    const float* W_hh       = (const float*)d_in[20];
    const float* b_hh       = (const float*)d_in[21];
    const float* addr_emb   = (const float*)d_in[22];
    const float* pid_emb    = (const float*)d_in[23];
    const float* sid_emb    = (const float*)d_in[24];
    const float* pid_ext_w  = (const float*)d_in[25];
    const float* pid_ext_b  = (const float*)d_in[26];
    const float* sid_ext_w  = (const float*)d_in[27];
    const float* sid_ext_b  = (const float*)d_in[28];
    const float* rp_ext_w   = (const float*)d_in[29];
    const float* rp_ext_b   = (const float*)d_in[30];
    float* out = (float*)d_out;

    // workspace layout (float slots, 16B-aligned chunks)
    float* ws = (float*)d_ws;
    size_t off = 0;
    float* W_ih_T   = ws + off; off += 432 * 1024;              // fp32
    ushort_t* Wb    = (ushort_t*)(ws + off); off += 131072;     // bf16 1024x256
    float* bias_all = ws + off; off += 7 * 1024;
    float* pid_rows = ws + off; off += 3 * 1024;
    float* sid_rows = ws + off; off += 2 * 1024;
    float* obs_emb  = ws + off; off += (size_t)BATCH * 400;
    ushort_t* obs_part = (ushort_t*)(ws + off); off += (size_t)BATCH * 512;  // bf16 Bx1024
    ushort_t* hb0 = (ushort_t*)(ws + off); off += (size_t)BATCH * 128;      // bf16 Bx256
    ushort_t* hbA = (ushort_t*)(ws + off); off += (size_t)BATCH * 128;
    ushort_t* hbB = (ushort_t*)(ws + off); off += (size_t)BATCH * 128;
    ushort_t* hbC = (ushort_t*)(ws + off); off += (size_t)BATCH * 128;
    float* c0 = ws + off; off += (size_t)BATCH * 256;
    float* cA = ws + off; off += (size_t)BATCH * 256;
    float* cB = ws + off; off += (size_t)BATCH * 256;
    float* cC = ws + off; off += (size_t)BATCH * 256;
    float* cD = ws + off; off += (size_t)BATCH * 256;   // dump for terminal c
    float* rp0      = ws + off; off += (size_t)BATCH * 2;
    float* rp0_emb  = ws + off; off += (size_t)BATCH * 16;
    float* w2t = ws + off; off += 10000;
    float* w3t = ws + off; off += 1600;
    float* w1p = ws + off; off += 384;
    ushort_t* Btg = (ushort_t*)(ws + off); off += 2304;  // 4608 bf16
    float* WsampT = W_ih_T + (size_t)400 * 1024;  // rows 400..415 of W_ih_T (fp32)

    prep_kernel<<<124, 256, 0, stream>>>(W_ih, W_hh, b_ih, b_hh, addr_emb,
                                         pid_emb, sid_emb, mlp_w2, mlp_w3,
                                         conv1_w, conv1_b, conv2_w,
                                         W_ih_T, Wb, bias_all, pid_rows,
                                         sid_rows, w2t, w3t, w1p, Btg);
    conv_kernel<<<BATCH, 512, 0, stream>>>(obs, w1p, Btg, conv2_b, obs_emb);
    obs_gemm<<<BATCH / 16, 512, 0, stream>>>(obs_emb, W_ih_T, obs_part);

    // step0 (aid 0): h=c=0 -> hb0, c0 (pid head on h0 folded into step1)
    step0_ew<<<BATCH, 256, 0, stream>>>(obs_part, bias_all + 0 * 1024, c0, hb0);

    // step1 (aid 1): hb0,c0 -> hbA,cA; samp pid; head = pid_logits(3) on h0 -> cols 0..2
    lstm_mfma<1, 3><<<512, 512, 0, stream>>>(
        hb0, c0, hbA, cA, obs_part, bias_all + 1 * 1024,
        pid_rows, program_id, nullptr, nullptr, Wb,
        pid_ext_w, pid_ext_b, out, 0);
    // step2 (aid 4): hbA,cA -> hbB,cD; samp sid[shape_id]; head = sid(2) on h1 -> cols 3..4
    lstm_mfma<1, 2><<<512, 512, 0, stream>>>(
        hbA, cA, hbB, cD, obs_part, bias_all + 2 * 1024,
        sid_rows, shape_id, nullptr, nullptr, Wb,
        sid_ext_w, sid_ext_b, out, 3);
    // rp_b0 head on h2 (hbB) -> cols 5..6
    rp_head<<<64, 256, 0, stream>>>(hbB, rp_ext_w, rp_ext_b, eps_rp, out, 5, nullptr);
    // step1b (aid 2): hb0,c0 -> hbA,cA; samp pid; no head
    lstm_mfma<1, 0><<<512, 512, 0, stream>>>(
        hb0, c0, hbA, cA, obs_part, bias_all + 3 * 1024,
        pid_rows, program_id, nullptr, nullptr, Wb,
        nullptr, nullptr, out, 0);
    // step2b (aid 3): hbA,cA -> hbB,cB; samp sid[shape_id_0]; head = sid0(2) on h1b -> cols 7..8
    lstm_mfma<1, 2><<<512, 512, 0, stream>>>(
        hbA, cA, hbB, cB, obs_part, bias_all + 4 * 1024,
        sid_rows, shape_id_0, nullptr, nullptr, Wb,
        sid_ext_w, sid_ext_b, out, 7);
    // step3b (aid 5): hbB,cB -> hbC,cC; samp sid[shape_id_1]; head = sid1(2) on h2b -> cols 9..10
    lstm_mfma<1, 2><<<512, 512, 0, stream>>>(
        hbB, cB, hbC, cC, obs_part, bias_all + 5 * 1024,
        sid_rows, shape_id_1, nullptr, nullptr, Wb,
        sid_ext_w, sid_ext_b, out, 9);
    // rp0 head on h3b (hbC) -> cols 11..12, store rp0
    rp_head<<<64, 256, 0, stream>>>(hbC, rp_ext_w, rp_ext_b, eps_rp0, out, 11, rp0);
    mlp_kernel<<<BATCH, 128, 0, stream>>>(rp0, mlp_w1, mlp_b1, w2t, mlp_b2,
                                          w3t, mlp_b3, rp0_emb);
    // step4b (aid 6): hbC,cC -> hbB,cD; samp = rp0_emb @ WsampT; no head
    lstm_mfma<2, 0><<<512, 512, 0, stream>>>(
        hbC, cC, hbB, cD, obs_part, bias_all + 6 * 1024,
        nullptr, nullptr, rp0_emb, WsampT, Wb,
        nullptr, nullptr, out, 0);
    // rp1 head on h4b (hbB) -> cols 13..14
    rp_head<<<64, 256, 0, stream>>>(hbB, rp_ext_w, rp_ext_b, eps_rp1, out, 13, nullptr);
}